// Round 11
// baseline (103.912 us; speedup 1.0000x reference)
//
#include <hip/hip_runtime.h>
#include <hip/hip_bf16.h>

#define BB 64
#define TT 1024
#define NN 512
#define LISTCAP (1u << 18)

static constexpr float THR = 0.15f;
static constexpr float SQ    = 6.0f / 127.0f;   // fixed quant scale (±6 sigma range)
static constexpr float INVSQ = 127.0f / 6.0f;

typedef __attribute__((ext_vector_type(4))) int i32x4;

// async global->LDS, 16B per lane; dest = wave-uniform base + lane*16 (HW rule)
__device__ __forceinline__ void gload16(const void* g, void* lds_dst) {
    __builtin_amdgcn_global_load_lds(
        (const __attribute__((address_space(1))) unsigned int*)g,
        (__attribute__((address_space(3))) unsigned int*)lds_dst, 16, 0, 0);
}

// ---------------- kernel T: fused colsum + fp32->int8 BLOCKED transpose ----------
// Grid (BB, 8). Emits xq[b][g][s] = 4 KiB page holding cols [64g,64g+64) x
// k [64s,64s+64) int8 in the EXACT swizzled LDS image corr consumes:
//   byte(c,k) = c*64 + (((k>>4) ^ ((c>>1)&3))&3)*16 + (k&15)
// Quantization x = SQ*q + l (q clamped to +-127); residual l MEASURED per column:
// nl = ||l||, nh = SQ*||q|| -> sound Cauchy-Schwarz bound downstream even if
// clamping occurs. Also s1 (exact sum), dv (exact unnorm. variance); zeroes
// fired/cnt. Thread (w,l): col n0+l, t-runs of 8 -> 8B stores (half a 16B slot).
__global__ __launch_bounds__(512) void transpose_colsum(
    const float* __restrict__ x, char* __restrict__ xq,
    float* __restrict__ s1, float* __restrict__ dv,
    float* __restrict__ nh, float* __restrict__ nl,
    unsigned* __restrict__ fired, unsigned* __restrict__ cnt) {
    __shared__ float red[4][8][64];
    int b = blockIdx.x, ng = blockIdx.y;
    int n0 = ng * 64;
    int tid = threadIdx.x, w = tid >> 6, l = tid & 63;
    const float* xb = x + (size_t)b * TT * NN + n0 + l;
    float a1 = 0.f, a2 = 0.f, al = 0.f;
    int aq = 0;
    if (b == 0 && ng == 0 && tid == 64) *cnt = 0;

    // per-thread fixed byte position within a page (swizzle baked):
    char* pbase = xq + ((size_t)(b * 8 + ng) * 16) * 4096
                  + (unsigned)l * 64u
                  + ((((unsigned)(w >> 1)) ^ (((unsigned)l >> 1) & 3u)) << 4)
                  + (unsigned)(w & 1) * 8u;

    for (int tc = 0; tc < 2; ++tc) {
        #pragma unroll
        for (int i = 0; i < 8; ++i) {
            int t0 = tc * 512 + i * 64 + w * 8;
            unsigned lo = 0, hi = 0;
            #pragma unroll
            for (int j = 0; j < 8; ++j) {
                float v = xb[(size_t)(t0 + j) * NN];
                a1 += v;
                a2 += v * v;
                int q = __float2int_rn(v * INVSQ);
                q = q > 127 ? 127 : (q < -127 ? -127 : q);
                aq += q * q;
                float lr = fmaf((float)q, -SQ, v);   // measured residual
                al += lr * lr;
                unsigned byte = (unsigned)(q & 255);
                if (j < 4) lo |= byte << (8 * j);
                else       hi |= byte << (8 * (j - 4));
            }
            *(uint2*)(pbase + (size_t)(t0 >> 6) * 4096) = make_uint2(lo, hi);
        }
    }
    red[0][w][l] = a1; red[1][w][l] = a2; red[2][w][l] = (float)aq; red[3][w][l] = al;
    __syncthreads();
    if (tid < 64) {
        float r1 = 0.f, r2 = 0.f, rq = 0.f, rl = 0.f;
        #pragma unroll
        for (int k = 0; k < 8; ++k) {
            r1 += red[0][k][tid]; r2 += red[1][k][tid];
            rq += red[2][k][tid]; rl += red[3][k][tid];
        }
        size_t o = (size_t)b * NN + n0 + tid;
        s1[o] = r1;
        dv[o] = r2 - r1 * r1 * (1.0f / TT);   // exact unnormalized cov_ii
        nh[o] = SQ * sqrtf(rq);               // ||s*q||
        nl[o] = sqrtf(rl);                    // ||residual||
        fired[o] = 0u;
    }
}

// ---------------- kernel B: i8 MFMA SYRK (r10 skeleton, all volumes halved) -----
// 64x64 tile per 256-thr block: 2304 blocks (XCD-chunked swizzle), 4 waves of
// 32x32, dbuf LDS 16 KiB (2 x (A 4K | B 4K)). KT=64 via mfma_i32_16x16x64_i8 ->
// 16 K-steps (was 32). Staging: 1 contiguous gload16/wave/panel from the blocked
// pages (4 KiB = exact LDS image). ds offsets: same verified conflict-free
// geometry as bf16 rounds (64B col stride, 16B slot XOR), k-groups of 16 i8.
// 2-phase: STAGE(t+1,buf^1) -> COMPUTE(buf) -> __syncthreads. i32 accum exact.
// Epilogue: c = SQ^2*dot_q - s1_i*s1_j/T; exact C-S bound B = nh_i*nl_j +
// nl_i*nh_j + nl_i*nl_j + 1e-3*nh_i*nh_j; uncertain pairs -> exact cleanup.
__global__ __launch_bounds__(256, 8) void corr_mfma(
    const char* __restrict__ xq, const float* __restrict__ s1,
    const float* __restrict__ dv, const float* __restrict__ nh,
    const float* __restrict__ nl, unsigned* __restrict__ fired,
    unsigned* __restrict__ cnt, unsigned* __restrict__ list) {
    __shared__ uint4 ldsbuf[1024];          // 16 KiB
    char* base = (char*)ldsbuf;

    int id = blockIdx.x;
    int swz = ((id & 7) * 288) + (id >> 3);   // 2304 = 8*288
    int b = swz / 36;
    int u = swz % 36;
    int ti = 0, rem = u;
    while (rem >= (8 - ti)) { rem -= (8 - ti); ++ti; }
    int tj = ti + rem;
    int i0 = ti * 64, j0 = tj * 64;
    bool diag = (ti == tj);

    int tid = threadIdx.x;
    int wave = tid >> 6, lane = tid & 63;
    int rl = lane & 15, kg = lane >> 4;

    const char* srcA = xq + ((size_t)(b * 8 + ti) * 16) * 4096 + tid * 16;
    const char* srcB = xq + ((size_t)(b * 8 + tj) * 16) * 4096 + tid * 16;

    auto STAGE = [&](int s, int buf) {
        char* d = base + (buf << 13) + wave * 1024;
        gload16(srcA + (size_t)s * 4096, d);
        if (!diag) gload16(srcB + (size_t)s * 4096, d + 4096);
    };

    int wr = wave >> 1, wc = wave & 1;
    bool skip_mm = diag && (wr == 1) && (wc == 0);

    unsigned aoff[2], boff[2];
    #pragma unroll
    for (int f = 0; f < 2; ++f) {
        unsigned ca = (unsigned)(32 * wr + 16 * f + rl);
        aoff[f] = ca * 64u + ((((unsigned)kg ^ ((ca >> 1) & 3u)) & 3u) << 4);
        unsigned cb2 = (unsigned)(32 * wc + 16 * f + rl);
        boff[f] = cb2 * 64u + ((((unsigned)kg ^ ((cb2 >> 1) & 3u)) & 3u) << 4);
    }
    unsigned bbase = diag ? 0u : 4096u;

    i32x4 acc[2][2];
    #pragma unroll
    for (int i = 0; i < 2; ++i)
        #pragma unroll
        for (int j = 0; j < 2; ++j)
            acc[i][j] = (i32x4)0;

    STAGE(0, 0);
    __syncthreads();

    for (int it = 0; it < 16; ++it) {
        if (it + 1 < 16) STAGE(it + 1, (it + 1) & 1);
        const char* cb = base + ((it & 1) << 13);
        if (!skip_mm) {
            i32x4 A[2], Bv[2];
            #pragma unroll
            for (int f = 0; f < 2; ++f) A[f] = *(const i32x4*)(cb + aoff[f]);
            #pragma unroll
            for (int f = 0; f < 2; ++f) Bv[f] = *(const i32x4*)(cb + bbase + boff[f]);
            #pragma unroll
            for (int fj = 0; fj < 2; ++fj)
                #pragma unroll
                for (int fi = 0; fi < 2; ++fi)
                    acc[fi][fj] = __builtin_amdgcn_mfma_i32_16x16x64_i8(
                        A[fi], Bv[fj], acc[fi][fj], 0, 0, 0);
        }
        __syncthreads();
    }

    // ---- epilogue ----
    const float thr2 = THR * THR;
    const float invT = 1.0f / TT;
    const float s2 = SQ * SQ;
    const float* s1b = s1 + (size_t)b * NN;
    const float* dvb = dv + (size_t)b * NN;
    const float* nhb = nh + (size_t)b * NN;
    const float* nlb = nl + (size_t)b * NN;
    unsigned* fb = fired + (size_t)b * NN;
    int rowb = i0 + 32 * wr + kg * 4;
    int colb = j0 + 32 * wc + rl;
    #pragma unroll
    for (int fj = 0; fj < 2; ++fj) {
        int gj = colb + 16 * fj;
        float sj = s1b[gj], djv = dvb[gj];
        float nhj = nhb[gj], nlj = nlb[gj];
        #pragma unroll
        for (int fi = 0; fi < 2; ++fi) {
            int gi0 = rowb + 16 * fi;
            #pragma unroll
            for (int r = 0; r < 4; ++r) {
                int gi = gi0 + r;
                if (gj > gi) {
                    float cc = s2 * (float)acc[fi][fj][r] - s1b[gi] * sj * invT;
                    float lim = thr2 * dvb[gi] * djv;
                    float nhi = nhb[gi], nli = nlb[gi];
                    float B = nli * nhj + nlj * nhi + nli * nlj
                              + 1e-3f * nhi * nhj;
                    float a = fabsf(cc);
                    float lo = a - B;
                    if (lo > 0.0f && lo * lo > lim) {
                        atomicOr(&fb[gi], 1u);
                    } else if ((a + B) * (a + B) > lim) {
                        unsigned idx = atomicAdd(cnt, 1u);
                        if (idx < LISTCAP)
                            list[idx] = ((unsigned)b << 18) | ((unsigned)gi << 9)
                                        | (unsigned)gj;
                    }
                }
            }
        }
    }
}

// ---------------- kernel B2: exact recompute of borderline pairs ----------------
__global__ __launch_bounds__(256) void cleanup_pairs(
    const float* __restrict__ x, const float* __restrict__ s1,
    const float* __restrict__ dv, const unsigned* __restrict__ cnt,
    const unsigned* __restrict__ list, unsigned* __restrict__ fired) {
    unsigned n = *cnt;
    if (n > LISTCAP) n = LISTCAP;
    int lane = threadIdx.x & 63;
    int gw = (blockIdx.x * 256 + threadIdx.x) >> 6;
    int nw = (gridDim.x * 256) >> 6;
    for (unsigned p = gw; p < n; p += nw) {
        unsigned e = list[p];
        int b = e >> 18, i = (e >> 9) & 511, j = e & 511;
        const float* xb = x + (size_t)b * TT * NN;
        double s = 0.0;
        for (int t = lane; t < TT; t += 64)
            s += (double)xb[(size_t)t * NN + i] * (double)xb[(size_t)t * NN + j];
        #pragma unroll
        for (int o = 32; o > 0; o >>= 1)
            s += __shfl_xor(s, o, 64);
        if (lane == 0) {
            double cov = s - (double)s1[(size_t)b * NN + i]
                             * (double)s1[(size_t)b * NN + j] / (double)TT;
            double lim = (double)THR * (double)THR
                         * (double)dv[(size_t)b * NN + i]
                         * (double)dv[(size_t)b * NN + j];
            if (cov * cov > lim) atomicOr(&fired[(size_t)b * NN + i], 1u);
        }
    }
}

// ---------------- kernel C: finalize mask ----------------
__global__ __launch_bounds__(512) void finalize_mask(
    const unsigned* __restrict__ fired, float* __restrict__ out) {
    int b = blockIdx.x;
    int n = threadIdx.x;
    unsigned f = fired[(size_t)b * NN + n];
    __shared__ int wsum[8];
    unsigned long long m = __ballot(f != 0u);
    int lane = n & 63;
    int w = n >> 6;
    if (lane == 0) wsum[w] = __popcll(m);
    __syncthreads();
    int cnt = 0;
    #pragma unroll
    for (int i = 0; i < 8; ++i) cnt += wsum[i];
    float val = (cnt == 0) ? 1.0f : ((cnt == 1) ? (f ? 1.0f : 0.0f) : 0.0f);
    out[(size_t)b * NN + n] = val;
}

extern "C" void kernel_launch(void* const* d_in, const int* in_sizes, int n_in,
                              void* d_out, int out_size, void* d_ws, size_t ws_size,
                              hipStream_t stream) {
    const float* x = (const float*)d_in[0];
    float* out = (float*)d_out;

    // ws layout (~34 MB)
    char* xq = (char*)d_ws;                              // BB*8*16*4096 = 32 MB
    float* s1 = (float*)(xq + (size_t)BB * NN * TT);     // B*N
    float* dv = s1 + (size_t)BB * NN;                    // B*N
    float* nh = dv + (size_t)BB * NN;                    // B*N
    float* nl = nh + (size_t)BB * NN;                    // B*N
    unsigned* fired = (unsigned*)(nl + (size_t)BB * NN); // B*N
    unsigned* cnt   = fired + (size_t)BB * NN;           // 16 (padded)
    unsigned* list  = cnt + 16;                          // LISTCAP

    transpose_colsum<<<dim3(BB, 8), 512, 0, stream>>>(x, xq, s1, dv, nh, nl,
                                                      fired, cnt);
    corr_mfma<<<dim3(2304), 256, 0, stream>>>(xq, s1, dv, nh, nl, fired, cnt, list);
    cleanup_pairs<<<128, 256, 0, stream>>>(x, s1, dv, cnt, list, fired);
    finalize_mask<<<BB, 512, 0, stream>>>(fired, out);
}

// Round 12
// 89.839 us; speedup vs baseline: 1.1567x; 1.1567x over previous
//
#include <hip/hip_runtime.h>
#include <hip/hip_bf16.h>

#define BB 64
#define TT 1024
#define NN 512
#define LISTCAP (1u << 18)

static constexpr float THR = 0.15f;
static constexpr float SQ    = 6.0f / 127.0f;   // fixed quant scale (±6 sigma range)
static constexpr float INVSQ = 127.0f / 6.0f;

typedef __attribute__((ext_vector_type(4))) int i32x4;

// async global->LDS, 16B per lane; dest = wave-uniform base + lane*16 (HW rule)
__device__ __forceinline__ void gload16(const void* g, void* lds_dst) {
    __builtin_amdgcn_global_load_lds(
        (const __attribute__((address_space(1))) unsigned int*)g,
        (__attribute__((address_space(3))) unsigned int*)lds_dst, 16, 0, 0);
}

// ---------------- kernel T: fused colsum + fp32->int8 page-assembled transpose ----
// Grid (BB, 8), 512 thr = 8 waves. Emits xq pages: page (b,g,s) = 4 KiB holding
// cols c'=0..63 of group g x k'=0..63 (t = 64s + k') in the EXACT swizzled LDS
// image corr consumes: byte(c',k') = c'*64 + (((k'>>4)^((c'>>1)&3))&3)*16 + (k'&15).
// WAVE-PRIVATE page assembly (fixes r11's 8B-scattered-RMW global writes, the
// measured 90us): wave w builds page s = tc*8+w in its own 4 KiB LDS slab
// (lane=col, 4x ds_write_b128 at baked-swizzle offsets -- each 8-lane group
// covers all 32 banks once, conflict-free), lgkmcnt(0), then drains LINEARLY:
// 4x 16B/lane = contiguous 4 KiB page (1 KB/wave-instr, zero RMW).
// Quantization x = SQ*q + l, q clamped +-127, residual MEASURED per column:
// nh = SQ*||q||, nl = ||l|| -> sound Cauchy-Schwarz bound downstream.
// Also exact s1, dv; zeroes fired/cnt.
__global__ __launch_bounds__(512) void transpose_colsum(
    const float* __restrict__ x, char* __restrict__ xq,
    float* __restrict__ s1, float* __restrict__ dv,
    float* __restrict__ nh, float* __restrict__ nl,
    unsigned* __restrict__ fired, unsigned* __restrict__ cnt) {
    __shared__ uint4 pagebuf[2048];         // 32 KiB: 8 wave-private pages
    __shared__ float red[4][8][64];         // 8 KiB
    int b = blockIdx.x, ng = blockIdx.y;
    int n0 = ng * 64;
    int tid = threadIdx.x, w = tid >> 6, l = tid & 63;
    const float* xb = x + (size_t)b * TT * NN + n0 + l;
    char* mypage = (char*)pagebuf + w * 4096;
    float a1 = 0.f, a2 = 0.f, al = 0.f, aqf = 0.f;
    unsigned swl = (((unsigned)l >> 1) & 3u);
    if (b == 0 && ng == 0 && tid == 64) *cnt = 0;

    for (int tc = 0; tc < 2; ++tc) {
        int tbase = tc * 512 + w * 64;       // this wave's page: t in [tbase, tbase+64)
        // ---- quantize 64 t's of col n0+l into the swizzled page image ----
        #pragma unroll
        for (int ks = 0; ks < 4; ++ks) {
            unsigned pk[4];
            #pragma unroll
            for (int qd = 0; qd < 4; ++qd) {
                unsigned pb = 0;
                #pragma unroll
                for (int j = 0; j < 4; ++j) {
                    float v = xb[(size_t)(tbase + ks * 16 + qd * 4 + j) * NN];
                    a1 += v;
                    a2 += v * v;
                    int q = __float2int_rn(v * INVSQ);
                    q = q > 127 ? 127 : (q < -127 ? -127 : q);
                    aqf += (float)(q * q);
                    float lr = fmaf((float)q, -SQ, v);   // measured residual
                    al += lr * lr;
                    pb |= ((unsigned)(q & 255)) << (8 * j);
                }
                pk[qd] = pb;
            }
            unsigned off = (unsigned)l * 64u + (((unsigned)ks ^ swl) << 4);
            *(uint4*)(mypage + off) = make_uint4(pk[0], pk[1], pk[2], pk[3]);
        }
        asm volatile("s_waitcnt lgkmcnt(0)" ::: "memory");   // page image complete
        __builtin_amdgcn_sched_barrier(0);
        // ---- drain page verbatim: contiguous 4 KiB global write ----
        char* gdst = xq + ((size_t)((b * 8 + ng) * 16) + tc * 8 + w) * 4096 + l * 16;
        #pragma unroll
        for (int it = 0; it < 4; ++it) {
            uint4 val = *(const uint4*)(mypage + it * 1024 + l * 16);
            *(uint4*)(gdst + (size_t)it * 1024) = val;
        }
        asm volatile("s_waitcnt lgkmcnt(0)" ::: "memory");   // reads done before next tc overwrite
        __builtin_amdgcn_sched_barrier(0);
    }
    red[0][w][l] = a1; red[1][w][l] = a2; red[2][w][l] = aqf; red[3][w][l] = al;
    __syncthreads();
    if (tid < 64) {
        float r1 = 0.f, r2 = 0.f, rq = 0.f, rl = 0.f;
        #pragma unroll
        for (int k = 0; k < 8; ++k) {
            r1 += red[0][k][tid]; r2 += red[1][k][tid];
            rq += red[2][k][tid]; rl += red[3][k][tid];
        }
        size_t o = (size_t)b * NN + n0 + tid;
        s1[o] = r1;
        dv[o] = r2 - r1 * r1 * (1.0f / TT);   // exact unnormalized cov_ii
        nh[o] = SQ * sqrtf(rq);               // ||s*q||
        nl[o] = sqrtf(rl);                    // ||residual||
        fired[o] = 0u;
    }
}

// ---------------- kernel B: i8 MFMA SYRK (r11-verified, ~10us measured) ----------
// 64x64 tile per 256-thr block: 2304 blocks (XCD-chunked swizzle -> per-XCD
// working set = 8 batches x 0.5 MB = 4 MB = L2-resident), 4 waves of 32x32,
// dbuf LDS 16 KiB. KT=64 via mfma_i32_16x16x64_i8, 16 K-steps. Staging: 1
// contiguous gload16/wave/panel from blocked pages. 2-phase: STAGE(t+1,buf^1)
// -> COMPUTE(buf) -> __syncthreads. i32 accum exact.
// Epilogue: c = SQ^2*dot_q - s1_i*s1_j/T; exact C-S bound; uncertain -> cleanup.
__global__ __launch_bounds__(256, 8) void corr_mfma(
    const char* __restrict__ xq, const float* __restrict__ s1,
    const float* __restrict__ dv, const float* __restrict__ nh,
    const float* __restrict__ nl, unsigned* __restrict__ fired,
    unsigned* __restrict__ cnt, unsigned* __restrict__ list) {
    __shared__ uint4 ldsbuf[1024];          // 16 KiB
    char* base = (char*)ldsbuf;

    int id = blockIdx.x;
    int swz = ((id & 7) * 288) + (id >> 3);   // 2304 = 8*288
    int b = swz / 36;
    int u = swz % 36;
    int ti = 0, rem = u;
    while (rem >= (8 - ti)) { rem -= (8 - ti); ++ti; }
    int tj = ti + rem;
    int i0 = ti * 64, j0 = tj * 64;
    bool diag = (ti == tj);

    int tid = threadIdx.x;
    int wave = tid >> 6, lane = tid & 63;
    int rl = lane & 15, kg = lane >> 4;

    const char* srcA = xq + ((size_t)(b * 8 + ti) * 16) * 4096 + tid * 16;
    const char* srcB = xq + ((size_t)(b * 8 + tj) * 16) * 4096 + tid * 16;

    auto STAGE = [&](int s, int buf) {
        char* d = base + (buf << 13) + wave * 1024;
        gload16(srcA + (size_t)s * 4096, d);
        if (!diag) gload16(srcB + (size_t)s * 4096, d + 4096);
    };

    int wr = wave >> 1, wc = wave & 1;
    bool skip_mm = diag && (wr == 1) && (wc == 0);

    unsigned aoff[2], boff[2];
    #pragma unroll
    for (int f = 0; f < 2; ++f) {
        unsigned ca = (unsigned)(32 * wr + 16 * f + rl);
        aoff[f] = ca * 64u + ((((unsigned)kg ^ ((ca >> 1) & 3u)) & 3u) << 4);
        unsigned cb2 = (unsigned)(32 * wc + 16 * f + rl);
        boff[f] = cb2 * 64u + ((((unsigned)kg ^ ((cb2 >> 1) & 3u)) & 3u) << 4);
    }
    unsigned bbase = diag ? 0u : 4096u;

    i32x4 acc[2][2];
    #pragma unroll
    for (int i = 0; i < 2; ++i)
        #pragma unroll
        for (int j = 0; j < 2; ++j)
            acc[i][j] = (i32x4)0;

    STAGE(0, 0);
    __syncthreads();

    for (int it = 0; it < 16; ++it) {
        if (it + 1 < 16) STAGE(it + 1, (it + 1) & 1);
        const char* cb = base + ((it & 1) << 13);
        if (!skip_mm) {
            i32x4 A[2], Bv[2];
            #pragma unroll
            for (int f = 0; f < 2; ++f) A[f] = *(const i32x4*)(cb + aoff[f]);
            #pragma unroll
            for (int f = 0; f < 2; ++f) Bv[f] = *(const i32x4*)(cb + bbase + boff[f]);
            #pragma unroll
            for (int fj = 0; fj < 2; ++fj)
                #pragma unroll
                for (int fi = 0; fi < 2; ++fi)
                    acc[fi][fj] = __builtin_amdgcn_mfma_i32_16x16x64_i8(
                        A[fi], Bv[fj], acc[fi][fj], 0, 0, 0);
        }
        __syncthreads();
    }

    // ---- epilogue ----
    const float thr2 = THR * THR;
    const float invT = 1.0f / TT;
    const float s2 = SQ * SQ;
    const float* s1b = s1 + (size_t)b * NN;
    const float* dvb = dv + (size_t)b * NN;
    const float* nhb = nh + (size_t)b * NN;
    const float* nlb = nl + (size_t)b * NN;
    unsigned* fb = fired + (size_t)b * NN;
    int rowb = i0 + 32 * wr + kg * 4;
    int colb = j0 + 32 * wc + rl;
    #pragma unroll
    for (int fj = 0; fj < 2; ++fj) {
        int gj = colb + 16 * fj;
        float sj = s1b[gj], djv = dvb[gj];
        float nhj = nhb[gj], nlj = nlb[gj];
        #pragma unroll
        for (int fi = 0; fi < 2; ++fi) {
            int gi0 = rowb + 16 * fi;
            #pragma unroll
            for (int r = 0; r < 4; ++r) {
                int gi = gi0 + r;
                if (gj > gi) {
                    float cc = s2 * (float)acc[fi][fj][r] - s1b[gi] * sj * invT;
                    float lim = thr2 * dvb[gi] * djv;
                    float nhi = nhb[gi], nli = nlb[gi];
                    float B = nli * nhj + nlj * nhi + nli * nlj
                              + 1e-3f * nhi * nhj;
                    float a = fabsf(cc);
                    float lo = a - B;
                    if (lo > 0.0f && lo * lo > lim) {
                        atomicOr(&fb[gi], 1u);
                    } else if ((a + B) * (a + B) > lim) {
                        unsigned idx = atomicAdd(cnt, 1u);
                        if (idx < LISTCAP)
                            list[idx] = ((unsigned)b << 18) | ((unsigned)gi << 9)
                                        | (unsigned)gj;
                    }
                }
            }
        }
    }
}

// ---------------- kernel B2: exact recompute of borderline pairs ----------------
__global__ __launch_bounds__(256) void cleanup_pairs(
    const float* __restrict__ x, const float* __restrict__ s1,
    const float* __restrict__ dv, const unsigned* __restrict__ cnt,
    const unsigned* __restrict__ list, unsigned* __restrict__ fired) {
    unsigned n = *cnt;
    if (n > LISTCAP) n = LISTCAP;
    int lane = threadIdx.x & 63;
    int gw = (blockIdx.x * 256 + threadIdx.x) >> 6;
    int nw = (gridDim.x * 256) >> 6;
    for (unsigned p = gw; p < n; p += nw) {
        unsigned e = list[p];
        int b = e >> 18, i = (e >> 9) & 511, j = e & 511;
        const float* xb = x + (size_t)b * TT * NN;
        double s = 0.0;
        for (int t = lane; t < TT; t += 64)
            s += (double)xb[(size_t)t * NN + i] * (double)xb[(size_t)t * NN + j];
        #pragma unroll
        for (int o = 32; o > 0; o >>= 1)
            s += __shfl_xor(s, o, 64);
        if (lane == 0) {
            double cov = s - (double)s1[(size_t)b * NN + i]
                             * (double)s1[(size_t)b * NN + j] / (double)TT;
            double lim = (double)THR * (double)THR
                         * (double)dv[(size_t)b * NN + i]
                         * (double)dv[(size_t)b * NN + j];
            if (cov * cov > lim) atomicOr(&fired[(size_t)b * NN + i], 1u);
        }
    }
}

// ---------------- kernel C: finalize mask ----------------
__global__ __launch_bounds__(512) void finalize_mask(
    const unsigned* __restrict__ fired, float* __restrict__ out) {
    int b = blockIdx.x;
    int n = threadIdx.x;
    unsigned f = fired[(size_t)b * NN + n];
    __shared__ int wsum[8];
    unsigned long long m = __ballot(f != 0u);
    int lane = n & 63;
    int w = n >> 6;
    if (lane == 0) wsum[w] = __popcll(m);
    __syncthreads();
    int cnt = 0;
    #pragma unroll
    for (int i = 0; i < 8; ++i) cnt += wsum[i];
    float val = (cnt == 0) ? 1.0f : ((cnt == 1) ? (f ? 1.0f : 0.0f) : 0.0f);
    out[(size_t)b * NN + n] = val;
}

extern "C" void kernel_launch(void* const* d_in, const int* in_sizes, int n_in,
                              void* d_out, int out_size, void* d_ws, size_t ws_size,
                              hipStream_t stream) {
    const float* x = (const float*)d_in[0];
    float* out = (float*)d_out;

    // ws layout (~34 MB)
    char* xq = (char*)d_ws;                              // BB*8*16*4096 = 32 MB
    float* s1 = (float*)(xq + (size_t)BB * NN * TT);     // B*N
    float* dv = s1 + (size_t)BB * NN;                    // B*N
    float* nh = dv + (size_t)BB * NN;                    // B*N
    float* nl = nh + (size_t)BB * NN;                    // B*N
    unsigned* fired = (unsigned*)(nl + (size_t)BB * NN); // B*N
    unsigned* cnt   = fired + (size_t)BB * NN;           // 16 (padded)
    unsigned* list  = cnt + 16;                          // LISTCAP

    transpose_colsum<<<dim3(BB, 8), 512, 0, stream>>>(x, xq, s1, dv, nh, nl,
                                                      fired, cnt);
    corr_mfma<<<dim3(2304), 256, 0, stream>>>(xq, s1, dv, nh, nl, fired, cnt, list);
    cleanup_pairs<<<128, 256, 0, stream>>>(x, s1, dv, cnt, list, fired);
    finalize_mask<<<BB, 512, 0, stream>>>(fired, out);
}